// Round 6
// baseline (1177.333 us; speedup 1.0000x reference)
//
#include <hip/hip_runtime.h>
#include <math.h>

#define D_MODEL 1024
#define D_FF    4096
#define NEXP    8
#define NTOK    8192
#define NASSIGN (NTOK*2)
#define NGBLK   (NTOK/4)   // gating blocks (4 tokens/block)

using short8 = __attribute__((ext_vector_type(8))) short;
using short4v = __attribute__((ext_vector_type(4))) short;
using f32x4  = __attribute__((ext_vector_type(4))) float;

__device__ __forceinline__ short f2bf(float f) {
  unsigned u = __float_as_uint(f);
  unsigned r = (u + 0x7fffu + ((u >> 16) & 1u)) >> 16;
  return (short)r;
}

__device__ __forceinline__ void gload_lds16(const void* g, void* l) {
  __builtin_amdgcn_global_load_lds((const __attribute__((address_space(1))) void*)g,
                                   (__attribute__((address_space(3))) void*)l, 16, 0, 0);
}

// fast erf-gelu: Abramowitz-Stegun 7.1.26, |eps| <= 1.5e-7
__device__ __forceinline__ float gelu_f(float x) {
  float z = 0.70710678118f * x;
  float a = fabsf(z);
  float t = 1.0f / (1.0f + 0.3275911f * a);
  float p = t * (0.254829592f + t * (-0.284496736f + t * (1.421413741f +
            t * (-1.453152027f + t * 1.061405429f))));
  float er = 1.0f - p * __expf(-a * a);
  er = copysignf(er, z);
  return 0.5f * x * (1.0f + er);
}

// ---------------- zero control ----------------
__global__ void zero_kernel(int* ctrl) {
  int i = threadIdx.x;
  if (i < 24) ctrl[i] = 0;   // cnt[8], cursor[8], off[8]
}

// ---------------- transpose + convert: in[e][R][C] fp32 -> out[e][C][R] bf16 ----------------
__global__ __launch_bounds__(256) void transpose_conv(const float* __restrict__ in, short* __restrict__ out,
                                                      int R, int C) {
  __shared__ float t[64][65];
  int e = blockIdx.z;
  size_t base = (size_t)e * R * C;
  int r0 = blockIdx.y * 64, c0 = blockIdx.x * 64;
  int lr = threadIdx.x >> 6, lc = threadIdx.x & 63;
#pragma unroll
  for (int j = 0; j < 16; ++j) {
    int rr = lr + j * 4;
    t[rr][lc] = in[base + (size_t)(r0 + rr) * C + c0 + lc];
  }
  __syncthreads();
#pragma unroll
  for (int j = 0; j < 16; ++j) {
    int oc = lr + j * 4;
    out[base + (size_t)(c0 + oc) * R + r0 + lc] = f2bf(t[lc][oc]);
  }
}

// ---------------- gating: one wave per token; also emits xb (bf16 copy of x) ----------------
__global__ __launch_bounds__(256) void gating_kernel(const float* __restrict__ x, const float* __restrict__ Wg,
                                                     int* __restrict__ assign_e, float* __restrict__ assign_w,
                                                     int* __restrict__ cnt_part, float* __restrict__ psum_part,
                                                     ushort4* __restrict__ xb4) {
  __shared__ float l_ps[NEXP];
  __shared__ int   l_cnt[NEXP];
  int tid = threadIdx.x, wv = tid >> 6, lane = tid & 63;
  if (tid < NEXP) { l_ps[tid] = 0.f; l_cnt[tid] = 0; }
  __syncthreads();

  int t = blockIdx.x * 4 + wv;
  const float4* xr = (const float4*)(x + (size_t)t * D_MODEL);
  float acc[NEXP];
#pragma unroll
  for (int e = 0; e < NEXP; ++e) acc[e] = 0.f;
#pragma unroll
  for (int i = 0; i < 4; ++i) {
    int c4 = lane + 64 * i;
    float4 v = xr[c4];
    ushort4 o;
    o.x = (unsigned short)f2bf(v.x); o.y = (unsigned short)f2bf(v.y);
    o.z = (unsigned short)f2bf(v.z); o.w = (unsigned short)f2bf(v.w);
    xb4[(size_t)t * 256 + c4] = o;
    const float* wr = Wg + c4 * 4 * NEXP;
#pragma unroll
    for (int j = 0; j < 4; ++j) {
      float xv = (&v.x)[j];
#pragma unroll
      for (int e = 0; e < NEXP; ++e) acc[e] += xv * wr[j * NEXP + e];
    }
  }
#pragma unroll
  for (int off = 32; off; off >>= 1)
#pragma unroll
    for (int e = 0; e < NEXP; ++e) acc[e] += __shfl_down(acc[e], off);

  if (lane == 0) {
    float m = acc[0];
#pragma unroll
    for (int e = 1; e < NEXP; ++e) m = fmaxf(m, acc[e]);
    float p[NEXP], s = 0.f;
#pragma unroll
    for (int e = 0; e < NEXP; ++e) { p[e] = expf(acc[e] - m); s += p[e]; }
    float inv = 1.f / s;
#pragma unroll
    for (int e = 0; e < NEXP; ++e) p[e] *= inv;
    int i0 = 0; float v0 = p[0];
#pragma unroll
    for (int e = 1; e < NEXP; ++e) if (p[e] > v0) { v0 = p[e]; i0 = e; }
    int i1 = -1; float v1 = -1.f;
#pragma unroll
    for (int e = 0; e < NEXP; ++e) if (e != i0 && p[e] > v1) { v1 = p[e]; i1 = e; }
    float denom = 1.f / (v0 + v1 + 1e-9f);
    assign_e[2 * t] = i0;     assign_w[2 * t] = v0 * denom;
    assign_e[2 * t + 1] = i1; assign_w[2 * t + 1] = v1 * denom;
    atomicAdd(&l_cnt[i0], 1);
    atomicAdd(&l_cnt[i1], 1);
#pragma unroll
    for (int e = 0; e < NEXP; ++e) atomicAdd(&l_ps[e], p[e]);
  }
  __syncthreads();
  if (tid < NEXP) {
    psum_part[blockIdx.x * NEXP + tid] = l_ps[tid];
    cnt_part[blockIdx.x * NEXP + tid] = l_cnt[tid];
  }
}

// ---------------- scan: reduce partials -> cnt/offs + aux loss ----------------
__global__ __launch_bounds__(256) void scan_kernel(const int* __restrict__ cnt_part, const float* __restrict__ psum_part,
                                                   int* __restrict__ cnt, int* __restrict__ offs,
                                                   float* __restrict__ aux_out) {
  __shared__ float sp[256];
  __shared__ int   sc[256];
  int tid = threadIdx.x;
  int e = tid & 7, c = tid >> 3;
  float fs = 0.f; int is = 0;
  for (int b = c; b < NGBLK; b += 32) {
    fs += psum_part[b * NEXP + e];
    is += cnt_part[b * NEXP + e];
  }
  sp[tid] = fs; sc[tid] = is;
  __syncthreads();
  if (tid < NEXP) {
    float f = 0.f; int n = 0;
    for (int c2 = 0; c2 < 32; ++c2) { f += sp[c2 * 8 + tid]; n += sc[c2 * 8 + tid]; }
    cnt[tid] = n; sp[tid] = f;
  }
  __syncthreads();
  if (tid == 0) {
    int o = 0; float aux = 0.f;
    for (int e2 = 0; e2 < NEXP; ++e2) {
      offs[e2] = o; o += cnt[e2];
      aux += (float)cnt[e2] * sp[e2];
    }
    aux_out[0] = aux * (float)NEXP / ((float)NTOK * (float)NTOK);
  }
}

// ---------------- scatter: compact assignments per expert ----------------
__global__ __launch_bounds__(256) void scatter_kernel(const int* __restrict__ assign_e,
                                                      const int* __restrict__ offs, int* __restrict__ cursor,
                                                      int* __restrict__ slot_tok, int* __restrict__ slot_of) {
  __shared__ int lhist[NEXP], lbase[NEXP];
  int tid = threadIdx.x;
  int a = blockIdx.x * 256 + tid;
  if (tid < NEXP) lhist[tid] = 0;
  __syncthreads();
  int e = assign_e[a];
  int lp = atomicAdd(&lhist[e], 1);
  __syncthreads();
  if (tid < NEXP) lbase[tid] = atomicAdd(&cursor[tid], lhist[tid]);
  __syncthreads();
  int s = offs[e] + lbase[e] + lp;
  slot_tok[s] = a >> 1;
  slot_of[a] = s;
}

// ================= 128x256 tile, BK=32, 4 waves, dbuf, single-barrier 2-phase =================
// R4-proven race-free schedule (stage-next FIRST -> ds_read -> MFMA -> vmcnt(0) -> barrier).
// 48 KiB LDS + 256 thr -> 3 blocks/CU = 12 waves/CU (the R4 latency-hiding regime).
// Panel-balanced XCD swizzle: XCD k runs panels (e=(lp+k)&7, ft=lp), rt innermost ->
//   512 KB B-panel L2-resident across rt; every XCD gets all experts (no imbalance tail).
// k-slot swizzle (0 conflicts, verified R3-R5): chunk c of row r lives at slot c ^ ((r>>1)&3).
template<int KD, int ND, int EPI>
__global__ __launch_bounds__(256, 3) void gemmT(
    const short* __restrict__ Asrc, const short* __restrict__ Bsrc,
    const float* __restrict__ bias, const int* __restrict__ slot_tok,
    const int* __restrict__ cnt, const int* __restrict__ offs,
    void* __restrict__ OutP)
{
  constexpr int NT = KD / 32;
  __shared__ short As[2][128 * 32];   // 8 KB per buf
  __shared__ short Bs[2][256 * 32];   // 16 KB per buf

  int bid = blockIdx.x;
  int xcd = bid & 7, j = bid >> 3;
  int lp = j >> 6, rt = j & 63;       // rt innermost on each XCD
  int ft = lp;
  int e = (lp + xcd) & 7;
  int cn = cnt[e];
  if (rt * 128 >= cn) return;
  int off = offs[e];
  int tid = threadIdx.x, l = tid & 63, wn = tid >> 6;   // wave wn owns cols wn*64..+64
  int l15 = l & 15;

  // staging sources (k-chunk pre-swizzled)
  int srow = tid >> 2;
  int sw8 = ((tid & 3) ^ ((tid >> 3) & 3)) * 8;
  int g0 = rt * 128 + srow, g1 = g0 + 64;
  int i0 = g0 < cn ? g0 : cn - 1;
  int i1 = g1 < cn ? g1 : cn - 1;
  const short *a0, *a1;
  if (EPI == 0) {
    a0 = Asrc + (size_t)slot_tok[off + i0] * KD + sw8;
    a1 = Asrc + (size_t)slot_tok[off + i1] * KD + sw8;
  } else {
    a0 = Asrc + (size_t)(off + i0) * KD + sw8;
    a1 = Asrc + (size_t)(off + i1) * KD + sw8;
  }
  const short* bb = Bsrc + (size_t)e * ND * KD + (size_t)(ft * 256) * KD + sw8;
  const short* b0 = bb + (size_t)(srow)       * KD;
  const short* b1 = bb + (size_t)(srow + 64)  * KD;
  const short* b2 = bb + (size_t)(srow + 128) * KD;
  const short* b3 = bb + (size_t)(srow + 192) * KD;

  // prologue: stage tile 0 into buf 0
  {
    char* dA = (char*)As[0] + tid * 16;
    char* dB = (char*)Bs[0] + tid * 16;
    gload_lds16(a0, dA); gload_lds16(a1, dA + 4096);
    gload_lds16(b0, dB); gload_lds16(b1, dB + 4096);
    gload_lds16(b2, dB + 8192); gload_lds16(b3, dB + 12288);
    a0 += 32; a1 += 32; b0 += 32; b1 += 32; b2 += 32; b3 += 32;
  }
  asm volatile("s_waitcnt vmcnt(0)" ::: "memory");
  __syncthreads();

  int cs8 = ((l >> 4) ^ ((l >> 1) & 3)) * 8;   // read slot = wanted k-group XOR row-swizzle
  const short* Ard = &As[0][l15 * 32] + cs8;                // + m*512 for row m*16+l15
  const short* Brd = &Bs[0][(wn * 64 + l15) * 32] + cs8;    // + n*512
  f32x4 acc[8][4] = {};

  for (int t = 0; t < NT; ++t) {
    int cur = t & 1;
    if (t + 1 < NT) {   // stage next tile FIRST (latency hides under reads+MFMA)
      char* dA = (char*)As[cur ^ 1] + tid * 16;
      char* dB = (char*)Bs[cur ^ 1] + tid * 16;
      gload_lds16(a0, dA); gload_lds16(a1, dA + 4096);
      gload_lds16(b0, dB); gload_lds16(b1, dB + 4096);
      gload_lds16(b2, dB + 8192); gload_lds16(b3, dB + 12288);
      a0 += 32; a1 += 32; b0 += 32; b1 += 32; b2 += 32; b3 += 32;
    }
    const short* Ac = Ard + cur * 4096;
    const short* Bc = Brd + cur * 8192;
    short8 af[8], bq[4];
#pragma unroll
    for (int n = 0; n < 4; ++n) bq[n] = *(const short8*)(Bc + n * 512);
#pragma unroll
    for (int m = 0; m < 8; ++m) af[m] = *(const short8*)(Ac + m * 512);
    __builtin_amdgcn_s_setprio(1);
#pragma unroll
    for (int m = 0; m < 8; ++m)
#pragma unroll
      for (int n = 0; n < 4; ++n)   // transposed-C: D rows = cols, D cols = tokens
        acc[m][n] = __builtin_amdgcn_mfma_f32_16x16x32_bf16(bq[n], af[m], acc[m][n], 0, 0, 0);
    __builtin_amdgcn_s_setprio(0);
    asm volatile("s_waitcnt vmcnt(0)" ::: "memory");
    __syncthreads();
  }

  // epilogue: acc[m][n][j] -> out[tok = rt*128+m*16+l15][col = ft*256+wn*64+n*16+(l>>4)*4+j]
  int l4 = (l >> 4) << 2;
#pragma unroll
  for (int n = 0; n < 4; ++n) {
    int col = ft * 256 + wn * 64 + n * 16 + l4;
    f32x4 b4 = *(const f32x4*)&bias[e * ND + col];
#pragma unroll
    for (int m = 0; m < 8; ++m) {
      int tok = rt * 128 + m * 16 + l15;
      if (tok < cn) {
        if (EPI == 0) {
          short4v h;
#pragma unroll
          for (int jj = 0; jj < 4; ++jj) h[jj] = f2bf(gelu_f(acc[m][n][jj] + b4[jj]));
          *(short4v*)((short*)OutP + (size_t)(off + tok) * ND + col) = h;
        } else {
          f32x4 o;
#pragma unroll
          for (int jj = 0; jj < 4; ++jj) o[jj] = acc[m][n][jj] + b4[jj];
          *(f32x4*)((float*)OutP + (size_t)(off + tok) * ND + col) = o;
        }
      }
    }
  }
}

// ---------------- combine: out[t] = w0*y[s0] + w1*y[s1] ----------------
__global__ __launch_bounds__(256) void combine_kernel(const float* __restrict__ y, const int* __restrict__ slot_of,
                                                      const float* __restrict__ assign_w, float* __restrict__ out) {
  int t = blockIdx.x;
  int d4 = threadIdx.x;
  int s0 = slot_of[2 * t], s1 = slot_of[2 * t + 1];
  float w0 = assign_w[2 * t], w1 = assign_w[2 * t + 1];
  float4 a = ((const float4*)(y + (size_t)s0 * D_MODEL))[d4];
  float4 b = ((const float4*)(y + (size_t)s1 * D_MODEL))[d4];
  float4 o;
  o.x = w0 * a.x + w1 * b.x;
  o.y = w0 * a.y + w1 * b.y;
  o.z = w0 * a.z + w1 * b.z;
  o.w = w0 * a.w + w1 * b.w;
  ((float4*)(out + (size_t)t * D_MODEL))[d4] = o;
}

extern "C" void kernel_launch(void* const* d_in, const int* in_sizes, int n_in,
                              void* d_out, int out_size, void* d_ws, size_t ws_size,
                              hipStream_t stream) {
  const float* x  = (const float*)d_in[0];
  const float* Wg = (const float*)d_in[1];
  const float* W1 = (const float*)d_in[2];
  const float* b1 = (const float*)d_in[3];
  const float* W2 = (const float*)d_in[4];
  const float* b2 = (const float*)d_in[5];
  float* out = (float*)d_out;
  char* ws = (char*)d_ws;

  // workspace layout (~285.6 MB)
  short* xb       = (short*)(ws);                       // 16,777,216 B
  short* w1t      = (short*)(ws + 16777216);            // 67,108,864 B  [e][f][k] bf16
  float* y        = (float*)(ws + 16777216);            // aliases w1t (dead after gemm1): 16384x1024 fp32
  short* w2t      = (short*)(ws + 83886080);            // 67,108,864 B  [e][d][ff] bf16
  short* H        = (short*)(ws + 150994944);           // 134,217,728 B 16384 x 4096 bf16
  int*   slot_tok = (int*)  (ws + 285212672);
  int*   assign_e = (int*)  (ws + 285278208);
  float* assign_w = (float*)(ws + 285343744);
  int*   slot_of  = (int*)  (ws + 285409280);
  int*   cnt_part = (int*)  (ws + 285474816);
  float* psum_part= (float*)(ws + 285540352);
  int*   ctrl     = (int*)  (ws + 285605888);
  int* cnt = ctrl; int* cursor = ctrl + 8; int* offs = ctrl + 16;

  zero_kernel<<<1, 64, 0, stream>>>(ctrl);
  transpose_conv<<<dim3(64, 16, NEXP), 256, 0, stream>>>(W1, w1t, D_MODEL, D_FF);
  transpose_conv<<<dim3(16, 64, NEXP), 256, 0, stream>>>(W2, w2t, D_FF, D_MODEL);
  gating_kernel<<<NGBLK, 256, 0, stream>>>(x, Wg, assign_e, assign_w, cnt_part, psum_part,
                                           (ushort4*)xb);
  scan_kernel<<<1, 256, 0, stream>>>(cnt_part, psum_part, cnt, offs, out + (out_size - 1));
  scatter_kernel<<<NASSIGN / 256, 256, 0, stream>>>(assign_e, offs, cursor, slot_tok, slot_of);
  // grid = 8 XCD * FT panels * 64 rt-slots; duds (rt beyond cn) exit immediately
  gemmT<D_MODEL, D_FF, 0><<<8 * (D_FF / 256) * 64, 256, 0, stream>>>(
      xb, w1t, b1, slot_tok, cnt, offs, H);
  gemmT<D_FF, D_MODEL, 1><<<8 * (D_MODEL / 256) * 64, 256, 0, stream>>>(
      H, w2t, b2, slot_tok, cnt, offs, y);
  combine_kernel<<<NTOK, 256, 0, stream>>>(y, slot_of, assign_w, out);
}

// Round 7
// 676.048 us; speedup vs baseline: 1.7415x; 1.7415x over previous
//
#include <hip/hip_runtime.h>
#include <math.h>

#define D_MODEL 1024
#define D_FF    4096
#define NEXP    8
#define NTOK    8192
#define NASSIGN (NTOK*2)
#define NGBLK   (NTOK/4)   // gating blocks (4 tokens/block)

using short8 = __attribute__((ext_vector_type(8))) short;
using short4v = __attribute__((ext_vector_type(4))) short;
using f32x4  = __attribute__((ext_vector_type(4))) float;

__device__ __forceinline__ short f2bf(float f) {
  unsigned u = __float_as_uint(f);
  unsigned r = (u + 0x7fffu + ((u >> 16) & 1u)) >> 16;
  return (short)r;
}

__device__ __forceinline__ void gload_lds16(const void* g, void* l) {
  __builtin_amdgcn_global_load_lds((const __attribute__((address_space(1))) void*)g,
                                   (__attribute__((address_space(3))) void*)l, 16, 0, 0);
}

// fast erf-gelu: Abramowitz-Stegun 7.1.26, |eps| <= 1.5e-7
__device__ __forceinline__ float gelu_f(float x) {
  float z = 0.70710678118f * x;
  float a = fabsf(z);
  float t = 1.0f / (1.0f + 0.3275911f * a);
  float p = t * (0.254829592f + t * (-0.284496736f + t * (1.421413741f +
            t * (-1.453152027f + t * 1.061405429f))));
  float er = 1.0f - p * __expf(-a * a);
  er = copysignf(er, z);
  return 0.5f * x * (1.0f + er);
}

// ---------------- zero control ----------------
__global__ void zero_kernel(int* ctrl) {
  int i = threadIdx.x;
  if (i < 24) ctrl[i] = 0;   // cnt[8], cursor[8], off[8]
}

// ---------------- transpose + convert: in[e][R][C] fp32 -> out[e][C][R] bf16 ----------------
__global__ __launch_bounds__(256) void transpose_conv(const float* __restrict__ in, short* __restrict__ out,
                                                      int R, int C) {
  __shared__ float t[64][65];
  int e = blockIdx.z;
  size_t base = (size_t)e * R * C;
  int r0 = blockIdx.y * 64, c0 = blockIdx.x * 64;
  int lr = threadIdx.x >> 6, lc = threadIdx.x & 63;
#pragma unroll
  for (int j = 0; j < 16; ++j) {
    int rr = lr + j * 4;
    t[rr][lc] = in[base + (size_t)(r0 + rr) * C + c0 + lc];
  }
  __syncthreads();
#pragma unroll
  for (int j = 0; j < 16; ++j) {
    int oc = lr + j * 4;
    out[base + (size_t)(c0 + oc) * R + r0 + lc] = f2bf(t[lc][oc]);
  }
}

// ---------------- gating: one wave per token; also emits xb (bf16 copy of x) ----------------
__global__ __launch_bounds__(256) void gating_kernel(const float* __restrict__ x, const float* __restrict__ Wg,
                                                     int* __restrict__ assign_e, float* __restrict__ assign_w,
                                                     int* __restrict__ cnt_part, float* __restrict__ psum_part,
                                                     ushort4* __restrict__ xb4) {
  __shared__ float l_ps[NEXP];
  __shared__ int   l_cnt[NEXP];
  int tid = threadIdx.x, wv = tid >> 6, lane = tid & 63;
  if (tid < NEXP) { l_ps[tid] = 0.f; l_cnt[tid] = 0; }
  __syncthreads();

  int t = blockIdx.x * 4 + wv;
  const float4* xr = (const float4*)(x + (size_t)t * D_MODEL);
  float acc[NEXP];
#pragma unroll
  for (int e = 0; e < NEXP; ++e) acc[e] = 0.f;
#pragma unroll
  for (int i = 0; i < 4; ++i) {
    int c4 = lane + 64 * i;
    float4 v = xr[c4];
    ushort4 o;
    o.x = (unsigned short)f2bf(v.x); o.y = (unsigned short)f2bf(v.y);
    o.z = (unsigned short)f2bf(v.z); o.w = (unsigned short)f2bf(v.w);
    xb4[(size_t)t * 256 + c4] = o;
    const float* wr = Wg + c4 * 4 * NEXP;
#pragma unroll
    for (int j = 0; j < 4; ++j) {
      float xv = (&v.x)[j];
#pragma unroll
      for (int e = 0; e < NEXP; ++e) acc[e] += xv * wr[j * NEXP + e];
    }
  }
#pragma unroll
  for (int off = 32; off; off >>= 1)
#pragma unroll
    for (int e = 0; e < NEXP; ++e) acc[e] += __shfl_down(acc[e], off);

  if (lane == 0) {
    float m = acc[0];
#pragma unroll
    for (int e = 1; e < NEXP; ++e) m = fmaxf(m, acc[e]);
    float p[NEXP], s = 0.f;
#pragma unroll
    for (int e = 0; e < NEXP; ++e) { p[e] = expf(acc[e] - m); s += p[e]; }
    float inv = 1.f / s;
#pragma unroll
    for (int e = 0; e < NEXP; ++e) p[e] *= inv;
    int i0 = 0; float v0 = p[0];
#pragma unroll
    for (int e = 1; e < NEXP; ++e) if (p[e] > v0) { v0 = p[e]; i0 = e; }
    int i1 = -1; float v1 = -1.f;
#pragma unroll
    for (int e = 0; e < NEXP; ++e) if (e != i0 && p[e] > v1) { v1 = p[e]; i1 = e; }
    float denom = 1.f / (v0 + v1 + 1e-9f);
    assign_e[2 * t] = i0;     assign_w[2 * t] = v0 * denom;
    assign_e[2 * t + 1] = i1; assign_w[2 * t + 1] = v1 * denom;
    atomicAdd(&l_cnt[i0], 1);
    atomicAdd(&l_cnt[i1], 1);
#pragma unroll
    for (int e = 0; e < NEXP; ++e) atomicAdd(&l_ps[e], p[e]);
  }
  __syncthreads();
  if (tid < NEXP) {
    psum_part[blockIdx.x * NEXP + tid] = l_ps[tid];
    cnt_part[blockIdx.x * NEXP + tid] = l_cnt[tid];
  }
}

// ---------------- scan: reduce partials -> cnt/offs + aux loss ----------------
__global__ __launch_bounds__(256) void scan_kernel(const int* __restrict__ cnt_part, const float* __restrict__ psum_part,
                                                   int* __restrict__ cnt, int* __restrict__ offs,
                                                   float* __restrict__ aux_out) {
  __shared__ float sp[256];
  __shared__ int   sc[256];
  int tid = threadIdx.x;
  int e = tid & 7, c = tid >> 3;
  float fs = 0.f; int is = 0;
  for (int b = c; b < NGBLK; b += 32) {
    fs += psum_part[b * NEXP + e];
    is += cnt_part[b * NEXP + e];
  }
  sp[tid] = fs; sc[tid] = is;
  __syncthreads();
  if (tid < NEXP) {
    float f = 0.f; int n = 0;
    for (int c2 = 0; c2 < 32; ++c2) { f += sp[c2 * 8 + tid]; n += sc[c2 * 8 + tid]; }
    cnt[tid] = n; sp[tid] = f;
  }
  __syncthreads();
  if (tid == 0) {
    int o = 0; float aux = 0.f;
    for (int e2 = 0; e2 < NEXP; ++e2) {
      offs[e2] = o; o += cnt[e2];
      aux += (float)cnt[e2] * sp[e2];
    }
    aux_out[0] = aux * (float)NEXP / ((float)NTOK * (float)NTOK);
  }
}

// ---------------- scatter: compact assignments per expert ----------------
__global__ __launch_bounds__(256) void scatter_kernel(const int* __restrict__ assign_e,
                                                      const int* __restrict__ offs, int* __restrict__ cursor,
                                                      int* __restrict__ slot_tok, int* __restrict__ slot_of) {
  __shared__ int lhist[NEXP], lbase[NEXP];
  int tid = threadIdx.x;
  int a = blockIdx.x * 256 + tid;
  if (tid < NEXP) lhist[tid] = 0;
  __syncthreads();
  int e = assign_e[a];
  int lp = atomicAdd(&lhist[e], 1);
  __syncthreads();
  if (tid < NEXP) lbase[tid] = atomicAdd(&cursor[tid], lhist[tid]);
  __syncthreads();
  int s = offs[e] + lbase[e] + lp;
  slot_tok[s] = a >> 1;
  slot_of[a] = s;
}

// ================= R4 kernel (proven): 128x128, BK=32, dbuf, single-barrier 2-phase =================
// ONE change this round: XCD panel-grouped ordering. Group g=(e,rt) is pinned to XCD (bid&7);
// its NP panel-blocks run CONSECUTIVELY on that XCD (p inner) so the 128-row A tile stays
// L2-resident across all panels (kills the 8x/32x A re-read that made R4 memory-bound).
// Experts rotate with gq so every XCD processes all experts (load balance).
// k-slot swizzle (0 conflicts, verified R3-R6): chunk c of row r lives at slot c ^ ((r>>1)&3).
// __launch_bounds__(256,4): 4 blocks/CU (VGPR 56, LDS 32KB allow) for cross-block latency overlap.
template<int KD, int ND, int EPI>
__global__ __launch_bounds__(256, 4) void gemm2p(
    const short* __restrict__ Asrc, const short* __restrict__ Bsrc,
    const float* __restrict__ bias, const int* __restrict__ slot_tok,
    const int* __restrict__ cnt, const int* __restrict__ offs,
    void* __restrict__ OutP)
{
  constexpr int NT = KD / 32;
  constexpr int NP = ND / 128;          // panels per group
  __shared__ short As[2][4096];         // [buf][128 rows][32 k]
  __shared__ short Bs[2][4096];

  // ---- panel-grouped XCD decode: bid = ((gq*NP)+p)*8 + glow ----
  int bid = blockIdx.x;
  int glow = bid & 7;
  int r = bid >> 3;
  int ft = r & (NP - 1);                // panel index, innermost on each XCD
  int gq = r / NP;                      // = rt
  int e = (glow + gq) & 7;              // rotate experts across gq for balance
  int rt = gq;
  int cn = cnt[e];
  if (rt * 128 >= cn) return;
  int off = offs[e];
  int tid = threadIdx.x, l = tid & 63, w = tid >> 6;
  int wr = w >> 1, wf = w & 1, l15 = l & 15;

  // staging: thread covers rows (tid>>2) and (tid>>2)+64; source chunk pre-swizzled
  int srow = tid >> 2;
  int sw8 = ((tid & 3) ^ ((tid >> 3) & 3)) * 8;
  int g0 = rt * 128 + srow, g1 = g0 + 64;
  int i0 = g0 < cn ? g0 : cn - 1;
  int i1 = g1 < cn ? g1 : cn - 1;
  const short *a0, *a1;
  if (EPI == 0) {
    a0 = Asrc + (size_t)slot_tok[off + i0] * KD + sw8;
    a1 = Asrc + (size_t)slot_tok[off + i1] * KD + sw8;
  } else {
    a0 = Asrc + (size_t)(off + i0) * KD + sw8;
    a1 = Asrc + (size_t)(off + i1) * KD + sw8;
  }
  const short* bbase = Bsrc + (size_t)e * ND * KD + (size_t)(ft * 128) * KD + sw8;
  const short* b0 = bbase + (size_t)srow * KD;
  const short* b1 = bbase + (size_t)(srow + 64) * KD;

  // prologue: stage tile 0 into buf 0
  gload_lds16(a0, (char*)As[0] + tid * 16); gload_lds16(a1, (char*)As[0] + 4096 + tid * 16);
  gload_lds16(b0, (char*)Bs[0] + tid * 16); gload_lds16(b1, (char*)Bs[0] + 4096 + tid * 16);
  a0 += 32; a1 += 32; b0 += 32; b1 += 32;
  asm volatile("s_waitcnt vmcnt(0)" ::: "memory");
  __syncthreads();

  int cs8 = ((l >> 4) ^ ((l >> 1) & 3)) * 8;   // read slot = wanted k-group XOR row-swizzle
  const short* Ard = &As[0][(wr * 64 + l15) * 32] + cs8;
  const short* Brd = &Bs[0][(wf * 64 + l15) * 32] + cs8;
  f32x4 acc[4][4] = {};

  for (int t = 0; t < NT; ++t) {
    int cur = t & 1;
    if (t + 1 < NT) {   // stage next tile FIRST (latency hides under reads+MFMA)
      char* dA = (char*)As[cur ^ 1] + tid * 16;
      char* dB = (char*)Bs[cur ^ 1] + tid * 16;
      gload_lds16(a0, dA); gload_lds16(a1, dA + 4096);
      gload_lds16(b0, dB); gload_lds16(b1, dB + 4096);
      a0 += 32; a1 += 32; b0 += 32; b1 += 32;
    }
    const short* Ac = Ard + cur * 4096;
    const short* Bc = Brd + cur * 4096;
    short8 af[4], bq[4];
#pragma unroll
    for (int m = 0; m < 4; ++m) af[m] = *(const short8*)(Ac + m * 512);
#pragma unroll
    for (int n = 0; n < 4; ++n) bq[n] = *(const short8*)(Bc + n * 512);
    __builtin_amdgcn_s_setprio(1);
#pragma unroll
    for (int m = 0; m < 4; ++m)
#pragma unroll
      for (int n = 0; n < 4; ++n)   // transposed-C: D rows = f/d cols, D cols = tokens
        acc[m][n] = __builtin_amdgcn_mfma_f32_16x16x32_bf16(bq[n], af[m], acc[m][n], 0, 0, 0);
    __builtin_amdgcn_s_setprio(0);
    asm volatile("s_waitcnt vmcnt(0)" ::: "memory");
    __syncthreads();
  }

  // epilogue: acc[m][n][j] = out[tok = rt*128+wr*64+m*16+l15][col = ft*128+wf*64+n*16+(l>>4)*4+j]
  int l4 = (l >> 4) << 2;
#pragma unroll
  for (int n = 0; n < 4; ++n) {
    int col = ft * 128 + wf * 64 + n * 16 + l4;
    f32x4 b4 = *(const f32x4*)&bias[e * ND + col];
#pragma unroll
    for (int m = 0; m < 4; ++m) {
      int tok = rt * 128 + wr * 64 + m * 16 + l15;
      if (tok < cn) {
        if (EPI == 0) {
          short4v h;
#pragma unroll
          for (int j = 0; j < 4; ++j) h[j] = f2bf(gelu_f(acc[m][n][j] + b4[j]));
          *(short4v*)((short*)OutP + (size_t)(off + tok) * ND + col) = h;
        } else {
          f32x4 o;
#pragma unroll
          for (int j = 0; j < 4; ++j) o[j] = acc[m][n][j] + b4[j];
          *(f32x4*)((float*)OutP + (size_t)(off + tok) * ND + col) = o;
        }
      }
    }
  }
}

// ---------------- combine: out[t] = w0*y[s0] + w1*y[s1] ----------------
__global__ __launch_bounds__(256) void combine_kernel(const float* __restrict__ y, const int* __restrict__ slot_of,
                                                      const float* __restrict__ assign_w, float* __restrict__ out) {
  int t = blockIdx.x;
  int d4 = threadIdx.x;
  int s0 = slot_of[2 * t], s1 = slot_of[2 * t + 1];
  float w0 = assign_w[2 * t], w1 = assign_w[2 * t + 1];
  float4 a = ((const float4*)(y + (size_t)s0 * D_MODEL))[d4];
  float4 b = ((const float4*)(y + (size_t)s1 * D_MODEL))[d4];
  float4 o;
  o.x = w0 * a.x + w1 * b.x;
  o.y = w0 * a.y + w1 * b.y;
  o.z = w0 * a.z + w1 * b.z;
  o.w = w0 * a.w + w1 * b.w;
  ((float4*)(out + (size_t)t * D_MODEL))[d4] = o;
}

extern "C" void kernel_launch(void* const* d_in, const int* in_sizes, int n_in,
                              void* d_out, int out_size, void* d_ws, size_t ws_size,
                              hipStream_t stream) {
  const float* x  = (const float*)d_in[0];
  const float* Wg = (const float*)d_in[1];
  const float* W1 = (const float*)d_in[2];
  const float* b1 = (const float*)d_in[3];
  const float* W2 = (const float*)d_in[4];
  const float* b2 = (const float*)d_in[5];
  float* out = (float*)d_out;
  char* ws = (char*)d_ws;

  // workspace layout (~285.6 MB)
  short* xb       = (short*)(ws);                       // 16,777,216 B
  short* w1t      = (short*)(ws + 16777216);            // 67,108,864 B  [e][f][k] bf16
  float* y        = (float*)(ws + 16777216);            // aliases w1t (dead after gemm1): 16384x1024 fp32
  short* w2t      = (short*)(ws + 83886080);            // 67,108,864 B  [e][d][ff] bf16
  short* H        = (short*)(ws + 150994944);           // 134,217,728 B 16384 x 4096 bf16
  int*   slot_tok = (int*)  (ws + 285212672);
  int*   assign_e = (int*)  (ws + 285278208);
  float* assign_w = (float*)(ws + 285343744);
  int*   slot_of  = (int*)  (ws + 285409280);
  int*   cnt_part = (int*)  (ws + 285474816);
  float* psum_part= (float*)(ws + 285540352);
  int*   ctrl     = (int*)  (ws + 285605888);
  int* cnt = ctrl; int* cursor = ctrl + 8; int* offs = ctrl + 16;

  zero_kernel<<<1, 64, 0, stream>>>(ctrl);
  transpose_conv<<<dim3(64, 16, NEXP), 256, 0, stream>>>(W1, w1t, D_MODEL, D_FF);
  transpose_conv<<<dim3(16, 64, NEXP), 256, 0, stream>>>(W2, w2t, D_FF, D_MODEL);
  gating_kernel<<<NGBLK, 256, 0, stream>>>(x, Wg, assign_e, assign_w, cnt_part, psum_part,
                                           (ushort4*)xb);
  scan_kernel<<<1, 256, 0, stream>>>(cnt_part, psum_part, cnt, offs, out + (out_size - 1));
  scatter_kernel<<<NASSIGN / 256, 256, 0, stream>>>(assign_e, offs, cursor, slot_tok, slot_of);
  // grid = 8 XCDs * 64 rt-groups * NP panels; panels of a group run consecutively on one XCD
  gemm2p<D_MODEL, D_FF, 0><<<8 * 64 * (D_FF / 128), 256, 0, stream>>>(
      xb, w1t, b1, slot_tok, cnt, offs, H);
  gemm2p<D_FF, D_MODEL, 1><<<8 * 64 * (D_MODEL / 128), 256, 0, stream>>>(
      H, w2t, b2, slot_tok, cnt, offs, y);
  combine_kernel<<<NTOK, 256, 0, stream>>>(y, slot_of, assign_w, out);
}

// Round 8
// 658.697 us; speedup vs baseline: 1.7874x; 1.0263x over previous
//
#include <hip/hip_runtime.h>
#include <math.h>

#define D_MODEL 1024
#define D_FF    4096
#define NEXP    8
#define NTOK    8192
#define NASSIGN (NTOK*2)
#define NGBLK   (NTOK/4)   // gating blocks (4 tokens/block)

using short8 = __attribute__((ext_vector_type(8))) short;
using short4v = __attribute__((ext_vector_type(4))) short;
using f32x4  = __attribute__((ext_vector_type(4))) float;

__device__ __forceinline__ short f2bf(float f) {
  unsigned u = __float_as_uint(f);
  unsigned r = (u + 0x7fffu + ((u >> 16) & 1u)) >> 16;
  return (short)r;
}

__device__ __forceinline__ void gload_lds16(const void* g, void* l) {
  __builtin_amdgcn_global_load_lds((const __attribute__((address_space(1))) void*)g,
                                   (__attribute__((address_space(3))) void*)l, 16, 0, 0);
}

// fast erf-gelu: Abramowitz-Stegun 7.1.26, |eps| <= 1.5e-7
__device__ __forceinline__ float gelu_f(float x) {
  float z = 0.70710678118f * x;
  float a = fabsf(z);
  float t = 1.0f / (1.0f + 0.3275911f * a);
  float p = t * (0.254829592f + t * (-0.284496736f + t * (1.421413741f +
            t * (-1.453152027f + t * 1.061405429f))));
  float er = 1.0f - p * __expf(-a * a);
  er = copysignf(er, z);
  return 0.5f * x * (1.0f + er);
}

// ---------------- zero control ----------------
__global__ void zero_kernel(int* ctrl) {
  int i = threadIdx.x;
  if (i < 24) ctrl[i] = 0;   // cnt[8], cursor[8], off[8]
}

// ---------------- transpose + convert: in[e][R][C] fp32 -> out[e][C][R] bf16 ----------------
__global__ __launch_bounds__(256) void transpose_conv(const float* __restrict__ in, short* __restrict__ out,
                                                      int R, int C) {
  __shared__ float t[64][65];
  int e = blockIdx.z;
  size_t base = (size_t)e * R * C;
  int r0 = blockIdx.y * 64, c0 = blockIdx.x * 64;
  int lr = threadIdx.x >> 6, lc = threadIdx.x & 63;
#pragma unroll
  for (int j = 0; j < 16; ++j) {
    int rr = lr + j * 4;
    t[rr][lc] = in[base + (size_t)(r0 + rr) * C + c0 + lc];
  }
  __syncthreads();
#pragma unroll
  for (int j = 0; j < 16; ++j) {
    int oc = lr + j * 4;
    out[base + (size_t)(c0 + oc) * R + r0 + lc] = f2bf(t[lc][oc]);
  }
}

// ---------------- gating: one wave per token; also emits xb (bf16 copy of x) ----------------
__global__ __launch_bounds__(256) void gating_kernel(const float* __restrict__ x, const float* __restrict__ Wg,
                                                     int* __restrict__ assign_e, float* __restrict__ assign_w,
                                                     int* __restrict__ cnt_part, float* __restrict__ psum_part,
                                                     ushort4* __restrict__ xb4) {
  __shared__ float l_ps[NEXP];
  __shared__ int   l_cnt[NEXP];
  int tid = threadIdx.x, wv = tid >> 6, lane = tid & 63;
  if (tid < NEXP) { l_ps[tid] = 0.f; l_cnt[tid] = 0; }
  __syncthreads();

  int t = blockIdx.x * 4 + wv;
  const float4* xr = (const float4*)(x + (size_t)t * D_MODEL);
  float acc[NEXP];
#pragma unroll
  for (int e = 0; e < NEXP; ++e) acc[e] = 0.f;
#pragma unroll
  for (int i = 0; i < 4; ++i) {
    int c4 = lane + 64 * i;
    float4 v = xr[c4];
    ushort4 o;
    o.x = (unsigned short)f2bf(v.x); o.y = (unsigned short)f2bf(v.y);
    o.z = (unsigned short)f2bf(v.z); o.w = (unsigned short)f2bf(v.w);
    xb4[(size_t)t * 256 + c4] = o;
    const float* wr = Wg + c4 * 4 * NEXP;
#pragma unroll
    for (int j = 0; j < 4; ++j) {
      float xv = (&v.x)[j];
#pragma unroll
      for (int e = 0; e < NEXP; ++e) acc[e] += xv * wr[j * NEXP + e];
    }
  }
#pragma unroll
  for (int off = 32; off; off >>= 1)
#pragma unroll
    for (int e = 0; e < NEXP; ++e) acc[e] += __shfl_down(acc[e], off);

  if (lane == 0) {
    float m = acc[0];
#pragma unroll
    for (int e = 1; e < NEXP; ++e) m = fmaxf(m, acc[e]);
    float p[NEXP], s = 0.f;
#pragma unroll
    for (int e = 0; e < NEXP; ++e) { p[e] = expf(acc[e] - m); s += p[e]; }
    float inv = 1.f / s;
#pragma unroll
    for (int e = 0; e < NEXP; ++e) p[e] *= inv;
    int i0 = 0; float v0 = p[0];
#pragma unroll
    for (int e = 1; e < NEXP; ++e) if (p[e] > v0) { v0 = p[e]; i0 = e; }
    int i1 = -1; float v1 = -1.f;
#pragma unroll
    for (int e = 0; e < NEXP; ++e) if (e != i0 && p[e] > v1) { v1 = p[e]; i1 = e; }
    float denom = 1.f / (v0 + v1 + 1e-9f);
    assign_e[2 * t] = i0;     assign_w[2 * t] = v0 * denom;
    assign_e[2 * t + 1] = i1; assign_w[2 * t + 1] = v1 * denom;
    atomicAdd(&l_cnt[i0], 1);
    atomicAdd(&l_cnt[i1], 1);
#pragma unroll
    for (int e = 0; e < NEXP; ++e) atomicAdd(&l_ps[e], p[e]);
  }
  __syncthreads();
  if (tid < NEXP) {
    psum_part[blockIdx.x * NEXP + tid] = l_ps[tid];
    cnt_part[blockIdx.x * NEXP + tid] = l_cnt[tid];
  }
}

// ---------------- scan: reduce partials -> cnt/offs + aux loss ----------------
__global__ __launch_bounds__(256) void scan_kernel(const int* __restrict__ cnt_part, const float* __restrict__ psum_part,
                                                   int* __restrict__ cnt, int* __restrict__ offs,
                                                   float* __restrict__ aux_out) {
  __shared__ float sp[256];
  __shared__ int   sc[256];
  int tid = threadIdx.x;
  int e = tid & 7, c = tid >> 3;
  float fs = 0.f; int is = 0;
  for (int b = c; b < NGBLK; b += 32) {
    fs += psum_part[b * NEXP + e];
    is += cnt_part[b * NEXP + e];
  }
  sp[tid] = fs; sc[tid] = is;
  __syncthreads();
  if (tid < NEXP) {
    float f = 0.f; int n = 0;
    for (int c2 = 0; c2 < 32; ++c2) { f += sp[c2 * 8 + tid]; n += sc[c2 * 8 + tid]; }
    cnt[tid] = n; sp[tid] = f;
  }
  __syncthreads();
  if (tid == 0) {
    int o = 0; float aux = 0.f;
    for (int e2 = 0; e2 < NEXP; ++e2) {
      offs[e2] = o; o += cnt[e2];
      aux += (float)cnt[e2] * sp[e2];
    }
    aux_out[0] = aux * (float)NEXP / ((float)NTOK * (float)NTOK);
  }
}

// ---------------- scatter: compact assignments per expert ----------------
__global__ __launch_bounds__(256) void scatter_kernel(const int* __restrict__ assign_e,
                                                      const int* __restrict__ offs, int* __restrict__ cursor,
                                                      int* __restrict__ slot_tok, int* __restrict__ slot_of) {
  __shared__ int lhist[NEXP], lbase[NEXP];
  int tid = threadIdx.x;
  int a = blockIdx.x * 256 + tid;
  if (tid < NEXP) lhist[tid] = 0;
  __syncthreads();
  int e = assign_e[a];
  int lp = atomicAdd(&lhist[e], 1);
  __syncthreads();
  if (tid < NEXP) lbase[tid] = atomicAdd(&cursor[tid], lhist[tid]);
  __syncthreads();
  int s = offs[e] + lbase[e] + lp;
  slot_tok[s] = a >> 1;
  slot_of[a] = s;
}

// ======= Asymmetric-tile GEMM: BM x BN, BK=32, 8 waves (wave-tile 64x64, acc 4x4 = 64 AGPR) =======
// R4's proven race-free schedule (stage-next FIRST -> ds_read -> 16 MFMA/wave -> vmcnt(0) -> barrier).
// 48 KiB LDS + <=128 regs (launch_bounds(512,4)) -> 2 blocks/CU = 16 waves/CU (R4's proven regime).
// Tile shapes cut compulsory traffic: gemm1 256Mx128N (w1t rereads /2), gemm2 128Mx256N (H rereads /2).
// k-slot swizzle (0 conflicts, verified R3-R7): chunk c of row r lives at slot c ^ ((r>>1)&3).
// EPI 0 additionally bounces H-stores through LDS for full-line writes (kills partial-line RFO).
template<int BM, int BN, int KD, int ND, int RT, int EPI>
__global__ __launch_bounds__(512, 4) void gemmT(
    const short* __restrict__ Asrc, const short* __restrict__ Bsrc,
    const float* __restrict__ bias, const int* __restrict__ slot_tok,
    const int* __restrict__ cnt, const int* __restrict__ offs,
    void* __restrict__ OutP)
{
  constexpr int NT = KD / 32;
  constexpr int NP = ND / BN;          // panels
  constexpr int WN = BN / 64;          // waves along N (2 or 4)
  constexpr int AISS = BM / 128;       // staging issues for A (1 or 2)
  constexpr int BISS = BN / 128;
  __shared__ short As[2][BM * 32];
  __shared__ short Bs[2][BN * 32];

  // grouped decode: bid = (q*NP + p)*8 + x ; group g = q*8+x -> (e, rt); panels p stride-8 (same XCD slot)
  int bid = blockIdx.x;
  int x = bid & 7, rr = bid >> 3;
  int ft = rr % NP, q = rr / NP;
  int g = q * 8 + x;
  int e = g / RT, rt = g % RT;
  int cn = cnt[e];
  if (rt * BM >= cn) return;
  int off = offs[e];
  int tid = threadIdx.x, l = tid & 63, w = tid >> 6;
  int wm = w / WN, wn = w % WN, l15 = l & 15;

  // staging sources: 4 threads/row (64 B), k-chunk pre-swizzled
  int srow = tid >> 2;
  int sw8 = ((tid & 3) ^ ((tid >> 3) & 3)) * 8;
  const short* ap[AISS];
  const short* bp[BISS];
#pragma unroll
  for (int is = 0; is < AISS; ++is) {
    int gr = rt * BM + srow + is * 128;
    int ic = gr < cn ? gr : cn - 1;
    if (EPI == 0) ap[is] = Asrc + (size_t)slot_tok[off + ic] * KD + sw8;
    else          ap[is] = Asrc + (size_t)(off + ic) * KD + sw8;
  }
  const short* bb = Bsrc + (size_t)e * ND * KD + (size_t)(ft * BN) * KD + sw8;
#pragma unroll
  for (int is = 0; is < BISS; ++is) bp[is] = bb + (size_t)(srow + is * 128) * KD;

  // prologue: stage tile 0 into buf 0
#pragma unroll
  for (int is = 0; is < AISS; ++is) { gload_lds16(ap[is], (char*)As[0] + is * 8192 + tid * 16); ap[is] += 32; }
#pragma unroll
  for (int is = 0; is < BISS; ++is) { gload_lds16(bp[is], (char*)Bs[0] + is * 8192 + tid * 16); bp[is] += 32; }
  asm volatile("s_waitcnt vmcnt(0)" ::: "memory");
  __syncthreads();

  int cs8 = ((l >> 4) ^ ((l >> 1) & 3)) * 8;   // read slot = wanted k-group XOR row-swizzle
  const short* Ard = &As[0][(wm * 64 + l15) * 32] + cs8;
  const short* Brd = &Bs[0][(wn * 64 + l15) * 32] + cs8;
  f32x4 acc[4][4] = {};

  for (int t = 0; t < NT; ++t) {
    int cur = t & 1;
    if (t + 1 < NT) {   // stage next tile FIRST (latency hides under reads+MFMA)
#pragma unroll
      for (int is = 0; is < AISS; ++is) { gload_lds16(ap[is], (char*)As[cur ^ 1] + is * 8192 + tid * 16); ap[is] += 32; }
#pragma unroll
      for (int is = 0; is < BISS; ++is) { gload_lds16(bp[is], (char*)Bs[cur ^ 1] + is * 8192 + tid * 16); bp[is] += 32; }
    }
    const short* Ac = Ard + cur * (BM * 32);
    const short* Bc = Brd + cur * (BN * 32);
    short8 af[4], bq[4];
#pragma unroll
    for (int m = 0; m < 4; ++m) af[m] = *(const short8*)(Ac + m * 512);
#pragma unroll
    for (int n = 0; n < 4; ++n) bq[n] = *(const short8*)(Bc + n * 512);
    __builtin_amdgcn_s_setprio(1);
#pragma unroll
    for (int m = 0; m < 4; ++m)
#pragma unroll
      for (int n = 0; n < 4; ++n)   // transposed-C: D rows = out cols, D cols = tokens
        acc[m][n] = __builtin_amdgcn_mfma_f32_16x16x32_bf16(bq[n], af[m], acc[m][n], 0, 0, 0);
    __builtin_amdgcn_s_setprio(0);
    asm volatile("s_waitcnt vmcnt(0)" ::: "memory");
    __syncthreads();
  }

  // epilogue: acc[m][n][j] -> out[tok = rt*BM + wm*64 + m*16 + l15][col = ft*BN + wn*64 + n*16 + (l>>4)*4 + j]
  int l4 = (l >> 4) << 2;
  if (EPI == 1) {      // y fp32: direct f32x4 stores (near-clean lines measured)
#pragma unroll
    for (int n = 0; n < 4; ++n) {
      int col = ft * BN + wn * 64 + n * 16 + l4;
      f32x4 b4 = *(const f32x4*)&bias[e * ND + col];
#pragma unroll
      for (int m = 0; m < 4; ++m) {
        int tok = rt * BM + wm * 64 + m * 16 + l15;
        if (tok < cn) {
          f32x4 o;
#pragma unroll
          for (int j = 0; j < 4; ++j) o[j] = acc[m][n][j] + b4[j];
          *(f32x4*)((float*)OutP + (size_t)(off + tok) * ND + col) = o;
        }
      }
    }
  } else {             // H bf16: gelu, then LDS-bounce for full-line coalesced stores
    short* bounce = &As[0][0];   // 16 KB slab: [64 rows][BN(=128) cols] bf16, 16B-cell XOR swizzle
    short* H = (short*)OutP;
#pragma unroll
    for (int m = 0; m < 4; ++m) {
      int lr = wm * 16 + l15;    // slab row (0..63)
#pragma unroll
      for (int n = 0; n < 4; ++n) {
        int colL = wn * 64 + n * 16 + l4;   // 0..127
        short4v h;
#pragma unroll
        for (int j = 0; j < 4; ++j)
          h[j] = f2bf(gelu_f(acc[m][n][j] + bias[e * ND + ft * BN + colL + j]));
        int cell = (colL >> 3) ^ (lr & 7);
        *(short4v*)&bounce[lr * 128 + cell * 8 + (colL & 4)] = h;
      }
      __syncthreads();
      // read out: 512 thr, 64 rows x 16 cells; 2 cells/thread -> 16B contiguous global stores
      int lr2 = tid >> 3;
      int tokb = rt * BM + (lr2 >> 4) * 64 + m * 16 + (lr2 & 15);
#pragma unroll
      for (int k = 0; k < 2; ++k) {
        int k2 = (tid & 7) * 2 + k;
        if (tokb < cn) {
          short8 v = *(const short8*)&bounce[lr2 * 128 + ((k2 ^ (lr2 & 7)) * 8)];
          *(short8*)&H[(size_t)(off + tokb) * ND + ft * BN + k2 * 8] = v;
        }
      }
      __syncthreads();
    }
  }
}

// ---------------- combine: out[t] = w0*y[s0] + w1*y[s1] ----------------
__global__ __launch_bounds__(256) void combine_kernel(const float* __restrict__ y, const int* __restrict__ slot_of,
                                                      const float* __restrict__ assign_w, float* __restrict__ out) {
  int t = blockIdx.x;
  int d4 = threadIdx.x;
  int s0 = slot_of[2 * t], s1 = slot_of[2 * t + 1];
  float w0 = assign_w[2 * t], w1 = assign_w[2 * t + 1];
  float4 a = ((const float4*)(y + (size_t)s0 * D_MODEL))[d4];
  float4 b = ((const float4*)(y + (size_t)s1 * D_MODEL))[d4];
  float4 o;
  o.x = w0 * a.x + w1 * b.x;
  o.y = w0 * a.y + w1 * b.y;
  o.z = w0 * a.z + w1 * b.z;
  o.w = w0 * a.w + w1 * b.w;
  ((float4*)(out + (size_t)t * D_MODEL))[d4] = o;
}

extern "C" void kernel_launch(void* const* d_in, const int* in_sizes, int n_in,
                              void* d_out, int out_size, void* d_ws, size_t ws_size,
                              hipStream_t stream) {
  const float* x  = (const float*)d_in[0];
  const float* Wg = (const float*)d_in[1];
  const float* W1 = (const float*)d_in[2];
  const float* b1 = (const float*)d_in[3];
  const float* W2 = (const float*)d_in[4];
  const float* b2 = (const float*)d_in[5];
  float* out = (float*)d_out;
  char* ws = (char*)d_ws;

  // workspace layout (~285.6 MB)
  short* xb       = (short*)(ws);                       // 16,777,216 B
  short* w1t      = (short*)(ws + 16777216);            // 67,108,864 B  [e][f][k] bf16
  float* y        = (float*)(ws + 16777216);            // aliases w1t (dead after gemm1): 16384x1024 fp32
  short* w2t      = (short*)(ws + 83886080);            // 67,108,864 B  [e][d][ff] bf16
  short* H        = (short*)(ws + 150994944);           // 134,217,728 B 16384 x 4096 bf16
  int*   slot_tok = (int*)  (ws + 285212672);
  int*   assign_e = (int*)  (ws + 285278208);
  float* assign_w = (float*)(ws + 285343744);
  int*   slot_of  = (int*)  (ws + 285409280);
  int*   cnt_part = (int*)  (ws + 285474816);
  float* psum_part= (float*)(ws + 285540352);
  int*   ctrl     = (int*)  (ws + 285605888);
  int* cnt = ctrl; int* cursor = ctrl + 8; int* offs = ctrl + 16;

  zero_kernel<<<1, 64, 0, stream>>>(ctrl);
  transpose_conv<<<dim3(64, 16, NEXP), 256, 0, stream>>>(W1, w1t, D_MODEL, D_FF);
  transpose_conv<<<dim3(16, 64, NEXP), 256, 0, stream>>>(W2, w2t, D_FF, D_MODEL);
  gating_kernel<<<NGBLK, 256, 0, stream>>>(x, Wg, assign_e, assign_w, cnt_part, psum_part,
                                           (ushort4*)xb);
  scan_kernel<<<1, 256, 0, stream>>>(cnt_part, psum_part, cnt, offs, out + (out_size - 1));
  scatter_kernel<<<NASSIGN / 256, 256, 0, stream>>>(assign_e, offs, cursor, slot_tok, slot_of);
  // gemm1: 256M x 128N, RT=32 (cn <= 8192 proven safe), grid = RT*NP*8
  gemmT<256, 128, D_MODEL, D_FF, 32, 0><<<32 * (D_FF / 128) * 8, 512, 0, stream>>>(
      xb, w1t, b1, slot_tok, cnt, offs, H);
  // gemm2: 128M x 256N, RT=64, grid = RT*NP*8
  gemmT<128, 256, D_FF, D_MODEL, 64, 1><<<64 * (D_MODEL / 256) * 8, 512, 0, stream>>>(
      H, w2t, b2, slot_tok, cnt, offs, y);
  combine_kernel<<<NTOK, 256, 0, stream>>>(y, slot_of, assign_w, out);
}

// Round 9
// 590.270 us; speedup vs baseline: 1.9946x; 1.1159x over previous
//
#include <hip/hip_runtime.h>
#include <math.h>

#define D_MODEL 1024
#define D_FF    4096
#define NEXP    8
#define NTOK    8192
#define NASSIGN (NTOK*2)
#define NGBLK   (NTOK/4)   // gating blocks (4 tokens/block)

using short8 = __attribute__((ext_vector_type(8))) short;
using short4v = __attribute__((ext_vector_type(4))) short;
using f32x4  = __attribute__((ext_vector_type(4))) float;

__device__ __forceinline__ short f2bf(float f) {
  unsigned u = __float_as_uint(f);
  unsigned r = (u + 0x7fffu + ((u >> 16) & 1u)) >> 16;
  return (short)r;
}

__device__ __forceinline__ void gload_lds16(const void* g, void* l) {
  __builtin_amdgcn_global_load_lds((const __attribute__((address_space(1))) void*)g,
                                   (__attribute__((address_space(3))) void*)l, 16, 0, 0);
}

// fast erf-gelu: Abramowitz-Stegun 7.1.26, |eps| <= 1.5e-7
__device__ __forceinline__ float gelu_f(float x) {
  float z = 0.70710678118f * x;
  float a = fabsf(z);
  float t = 1.0f / (1.0f + 0.3275911f * a);
  float p = t * (0.254829592f + t * (-0.284496736f + t * (1.421413741f +
            t * (-1.453152027f + t * 1.061405429f))));
  float er = 1.0f - p * __expf(-a * a);
  er = copysignf(er, z);
  return 0.5f * x * (1.0f + er);
}

// ---------------- zero control ----------------
__global__ void zero_kernel(int* ctrl) {
  int i = threadIdx.x;
  if (i < 24) ctrl[i] = 0;   // cnt[8], cursor[8], off[8]
}

// ---------------- transpose + convert: in[e][R][C] fp32 -> out[e][C][R] bf16 ----------------
__global__ __launch_bounds__(256) void transpose_conv(const float* __restrict__ in, short* __restrict__ out,
                                                      int R, int C) {
  __shared__ float t[64][65];
  int e = blockIdx.z;
  size_t base = (size_t)e * R * C;
  int r0 = blockIdx.y * 64, c0 = blockIdx.x * 64;
  int lr = threadIdx.x >> 6, lc = threadIdx.x & 63;
#pragma unroll
  for (int j = 0; j < 16; ++j) {
    int rr = lr + j * 4;
    t[rr][lc] = in[base + (size_t)(r0 + rr) * C + c0 + lc];
  }
  __syncthreads();
#pragma unroll
  for (int j = 0; j < 16; ++j) {
    int oc = lr + j * 4;
    out[base + (size_t)(c0 + oc) * R + r0 + lc] = f2bf(t[lc][oc]);
  }
}

// ---------------- gating: one wave per token; also emits xb (bf16 copy of x) ----------------
__global__ __launch_bounds__(256) void gating_kernel(const float* __restrict__ x, const float* __restrict__ Wg,
                                                     int* __restrict__ assign_e, float* __restrict__ assign_w,
                                                     int* __restrict__ cnt_part, float* __restrict__ psum_part,
                                                     ushort4* __restrict__ xb4) {
  __shared__ float l_ps[NEXP];
  __shared__ int   l_cnt[NEXP];
  int tid = threadIdx.x, wv = tid >> 6, lane = tid & 63;
  if (tid < NEXP) { l_ps[tid] = 0.f; l_cnt[tid] = 0; }
  __syncthreads();

  int t = blockIdx.x * 4 + wv;
  const float4* xr = (const float4*)(x + (size_t)t * D_MODEL);
  float acc[NEXP];
#pragma unroll
  for (int e = 0; e < NEXP; ++e) acc[e] = 0.f;
#pragma unroll
  for (int i = 0; i < 4; ++i) {
    int c4 = lane + 64 * i;
    float4 v = xr[c4];
    ushort4 o;
    o.x = (unsigned short)f2bf(v.x); o.y = (unsigned short)f2bf(v.y);
    o.z = (unsigned short)f2bf(v.z); o.w = (unsigned short)f2bf(v.w);
    xb4[(size_t)t * 256 + c4] = o;
    const float* wr = Wg + c4 * 4 * NEXP;
#pragma unroll
    for (int j = 0; j < 4; ++j) {
      float xv = (&v.x)[j];
#pragma unroll
      for (int e = 0; e < NEXP; ++e) acc[e] += xv * wr[j * NEXP + e];
    }
  }
#pragma unroll
  for (int off = 32; off; off >>= 1)
#pragma unroll
    for (int e = 0; e < NEXP; ++e) acc[e] += __shfl_down(acc[e], off);

  if (lane == 0) {
    float m = acc[0];
#pragma unroll
    for (int e = 1; e < NEXP; ++e) m = fmaxf(m, acc[e]);
    float p[NEXP], s = 0.f;
#pragma unroll
    for (int e = 0; e < NEXP; ++e) { p[e] = expf(acc[e] - m); s += p[e]; }
    float inv = 1.f / s;
#pragma unroll
    for (int e = 0; e < NEXP; ++e) p[e] *= inv;
    int i0 = 0; float v0 = p[0];
#pragma unroll
    for (int e = 1; e < NEXP; ++e) if (p[e] > v0) { v0 = p[e]; i0 = e; }
    int i1 = -1; float v1 = -1.f;
#pragma unroll
    for (int e = 0; e < NEXP; ++e) if (e != i0 && p[e] > v1) { v1 = p[e]; i1 = e; }
    float denom = 1.f / (v0 + v1 + 1e-9f);
    assign_e[2 * t] = i0;     assign_w[2 * t] = v0 * denom;
    assign_e[2 * t + 1] = i1; assign_w[2 * t + 1] = v1 * denom;
    atomicAdd(&l_cnt[i0], 1);
    atomicAdd(&l_cnt[i1], 1);
#pragma unroll
    for (int e = 0; e < NEXP; ++e) atomicAdd(&l_ps[e], p[e]);
  }
  __syncthreads();
  if (tid < NEXP) {
    psum_part[blockIdx.x * NEXP + tid] = l_ps[tid];
    cnt_part[blockIdx.x * NEXP + tid] = l_cnt[tid];
  }
}

// ---------------- scan: reduce partials -> cnt/offs + aux loss ----------------
__global__ __launch_bounds__(256) void scan_kernel(const int* __restrict__ cnt_part, const float* __restrict__ psum_part,
                                                   int* __restrict__ cnt, int* __restrict__ offs,
                                                   float* __restrict__ aux_out) {
  __shared__ float sp[256];
  __shared__ int   sc[256];
  int tid = threadIdx.x;
  int e = tid & 7, c = tid >> 3;
  float fs = 0.f; int is = 0;
  for (int b = c; b < NGBLK; b += 32) {
    fs += psum_part[b * NEXP + e];
    is += cnt_part[b * NEXP + e];
  }
  sp[tid] = fs; sc[tid] = is;
  __syncthreads();
  if (tid < NEXP) {
    float f = 0.f; int n = 0;
    for (int c2 = 0; c2 < 32; ++c2) { f += sp[c2 * 8 + tid]; n += sc[c2 * 8 + tid]; }
    cnt[tid] = n; sp[tid] = f;
  }
  __syncthreads();
  if (tid == 0) {
    int o = 0; float aux = 0.f;
    for (int e2 = 0; e2 < NEXP; ++e2) {
      offs[e2] = o; o += cnt[e2];
      aux += (float)cnt[e2] * sp[e2];
    }
    aux_out[0] = aux * (float)NEXP / ((float)NTOK * (float)NTOK);
  }
}

// ---------------- scatter: compact assignments per expert ----------------
__global__ __launch_bounds__(256) void scatter_kernel(const int* __restrict__ assign_e,
                                                      const int* __restrict__ offs, int* __restrict__ cursor,
                                                      int* __restrict__ slot_tok, int* __restrict__ slot_of) {
  __shared__ int lhist[NEXP], lbase[NEXP];
  int tid = threadIdx.x;
  int a = blockIdx.x * 256 + tid;
  if (tid < NEXP) lhist[tid] = 0;
  __syncthreads();
  int e = assign_e[a];
  int lp = atomicAdd(&lhist[e], 1);
  __syncthreads();
  if (tid < NEXP) lbase[tid] = atomicAdd(&cursor[tid], lhist[tid]);
  __syncthreads();
  int s = offs[e] + lbase[e] + lp;
  slot_tok[s] = a >> 1;
  slot_of[a] = s;
}

// ===== Asymmetric-tile GEMM, BK=32, 8 waves (wave-tile 64x64), 3-buffer distance-2 pipeline =====
// R9 change (one variable vs R8): counted vmcnt, never drained in steady state.
// Per step t: vmcnt(3) [tile t landed, t+1 in flight] -> raw s_barrier -> ds_read(t) ->
//             stage(t+2 into buf[(t+2)%3]) -> 16 MFMA.  Single barrier/step.
// Race audit: stage(t) writes buf[(t-1)%3]; all waves' t-1 ds_reads completed (lgkm data-dep
// before their MFMAs) before they reached barrier(t). Tile t's loads were issued at step t-2
// (~2 full steps earlier) -> load latency fully hidden.  LDS 72 KB dyn -> 2 blocks/CU.
// k-slot swizzle (0 conflicts, verified R3-R8): chunk c of row r lives at slot c ^ ((r>>1)&3).
// EPI 0 bounces H-stores through LDS for full-line writes (verified: WRITE 287->131 MB).
template<int BM, int BN, int KD, int ND, int RT, int EPI>
__global__ __launch_bounds__(512, 4) void gemmT(
    const short* __restrict__ Asrc, const short* __restrict__ Bsrc,
    const float* __restrict__ bias, const int* __restrict__ slot_tok,
    const int* __restrict__ cnt, const int* __restrict__ offs,
    void* __restrict__ OutP)
{
  constexpr int NT = KD / 32;
  constexpr int NP = ND / BN;          // panels
  constexpr int WN = BN / 64;          // waves along N (2 or 4)
  constexpr int AISS = BM / 128;       // staging issues for A (1 or 2)
  constexpr int BISS = BN / 128;
  constexpr int ABYT = BM * 64;        // bytes per A buffer
  constexpr int BBYT = BN * 64;
  extern __shared__ char ldsb[];       // [3][ABYT] A, then [3][BBYT] B  (72 KB)
  char* Abase = ldsb;
  char* Bbase = ldsb + 3 * ABYT;

  // grouped decode: bid = (q*NP + p)*8 + x ; group g = q*8+x -> (e, rt)
  int bid = blockIdx.x;
  int x = bid & 7, rr = bid >> 3;
  int ft = rr % NP, q = rr / NP;
  int g = q * 8 + x;
  int e = g / RT, rt = g % RT;
  int cn = cnt[e];
  if (rt * BM >= cn) return;
  int off = offs[e];
  int tid = threadIdx.x, l = tid & 63, w = tid >> 6;
  int wm = w / WN, wn = w % WN, l15 = l & 15;

  // staging sources: 4 threads/row (64 B), k-chunk pre-swizzled
  int srow = tid >> 2;
  int sw8 = ((tid & 3) ^ ((tid >> 3) & 3)) * 8;
  const short* ap[AISS];
  const short* bp[BISS];
#pragma unroll
  for (int is = 0; is < AISS; ++is) {
    int gr = rt * BM + srow + is * 128;
    int ic = gr < cn ? gr : cn - 1;
    if (EPI == 0) ap[is] = Asrc + (size_t)slot_tok[off + ic] * KD + sw8;
    else          ap[is] = Asrc + (size_t)(off + ic) * KD + sw8;
  }
  const short* bb = Bsrc + (size_t)e * ND * KD + (size_t)(ft * BN) * KD + sw8;
#pragma unroll
  for (int is = 0; is < BISS; ++is) bp[is] = bb + (size_t)(srow + is * 128) * KD;

  // prologue: stage tiles 0 and 1 into bufs 0,1 (3 loads/thread each)
#pragma unroll
  for (int p = 0; p < 2; ++p) {
#pragma unroll
    for (int is = 0; is < AISS; ++is) { gload_lds16(ap[is], Abase + p * ABYT + is * 8192 + tid * 16); ap[is] += 32; }
#pragma unroll
    for (int is = 0; is < BISS; ++is) { gload_lds16(bp[is], Bbase + p * BBYT + is * 8192 + tid * 16); bp[is] += 32; }
  }

  int cs8 = ((l >> 4) ^ ((l >> 1) & 3)) * 8;   // read slot = wanted k-group XOR row-swizzle
  const short* Ard = (const short*)Abase + (wm * 64 + l15) * 32 + cs8;
  const short* Brd = (const short*)Bbase + (wn * 64 + l15) * 32 + cs8;
  f32x4 acc[4][4] = {};

  int cur = 0;
  for (int t = 0; t < NT; ++t) {
    // tile t landed when only t+1's 3 loads remain outstanding
    if (t < NT - 1) { asm volatile("s_waitcnt vmcnt(3)" ::: "memory"); }
    else            { asm volatile("s_waitcnt vmcnt(0)" ::: "memory"); }
    asm volatile("s_barrier" ::: "memory");
    const short* Ac = Ard + cur * (ABYT / 2);
    const short* Bc = Brd + cur * (BBYT / 2);
    short8 af[4], bq[4];
#pragma unroll
    for (int m = 0; m < 4; ++m) af[m] = *(const short8*)(Ac + m * 512);
#pragma unroll
    for (int n = 0; n < 4; ++n) bq[n] = *(const short8*)(Bc + n * 512);
    if (t + 2 < NT) {   // stage tile t+2 into buf[(t+2)%3] (= buf[(t-1)%3], released above)
      int nb = (cur + 2 >= 3) ? cur - 1 : cur + 2;
#pragma unroll
      for (int is = 0; is < AISS; ++is) { gload_lds16(ap[is], Abase + nb * ABYT + is * 8192 + tid * 16); ap[is] += 32; }
#pragma unroll
      for (int is = 0; is < BISS; ++is) { gload_lds16(bp[is], Bbase + nb * BBYT + is * 8192 + tid * 16); bp[is] += 32; }
    }
    __builtin_amdgcn_s_setprio(1);
#pragma unroll
    for (int m = 0; m < 4; ++m)
#pragma unroll
      for (int n = 0; n < 4; ++n)   // transposed-C: D rows = out cols, D cols = tokens
        acc[m][n] = __builtin_amdgcn_mfma_f32_16x16x32_bf16(bq[n], af[m], acc[m][n], 0, 0, 0);
    __builtin_amdgcn_s_setprio(0);
    cur = (cur == 2) ? 0 : cur + 1;
  }

  // epilogue: acc[m][n][j] -> out[tok = rt*BM + wm*64 + m*16 + l15][col = ft*BN + wn*64 + n*16 + (l>>4)*4 + j]
  int l4 = (l >> 4) << 2;
  if (EPI == 1) {      // y fp32: direct f32x4 stores
#pragma unroll
    for (int n = 0; n < 4; ++n) {
      int col = ft * BN + wn * 64 + n * 16 + l4;
      f32x4 b4 = *(const f32x4*)&bias[e * ND + col];
#pragma unroll
      for (int m = 0; m < 4; ++m) {
        int tok = rt * BM + wm * 64 + m * 16 + l15;
        if (tok < cn) {
          f32x4 o;
#pragma unroll
          for (int j = 0; j < 4; ++j) o[j] = acc[m][n][j] + b4[j];
          *(f32x4*)((float*)OutP + (size_t)(off + tok) * ND + col) = o;
        }
      }
    }
  } else {             // H bf16: gelu, then LDS-bounce for full-line coalesced stores
    __syncthreads();                       // all compute done before reusing buf0 slab
    short* bounce = (short*)Abase;         // 16 KB slab (A-buf0; last tile used buf (NT-1)%3 = 1)
    short* H = (short*)OutP;
#pragma unroll
    for (int m = 0; m < 4; ++m) {
      int lr = wm * 16 + l15;    // slab row (0..63)
#pragma unroll
      for (int n = 0; n < 4; ++n) {
        int colL = wn * 64 + n * 16 + l4;   // 0..127
        short4v h;
#pragma unroll
        for (int j = 0; j < 4; ++j)
          h[j] = f2bf(gelu_f(acc[m][n][j] + bias[e * ND + ft * BN + colL + j]));
        int cell = (colL >> 3) ^ (lr & 7);
        *(short4v*)&bounce[lr * 128 + cell * 8 + (colL & 4)] = h;
      }
      __syncthreads();
      // read out: 512 thr, 64 rows x 16 cells; 2 cells/thread -> 16B contiguous global stores
      int lr2 = tid >> 3;
      int tokb = rt * BM + (lr2 >> 4) * 64 + m * 16 + (lr2 & 15);
#pragma unroll
      for (int k = 0; k < 2; ++k) {
        int k2 = (tid & 7) * 2 + k;
        if (tokb < cn) {
          short8 v = *(const short8*)&bounce[lr2 * 128 + ((k2 ^ (lr2 & 7)) * 8)];
          *(short8*)&H[(size_t)(off + tokb) * ND + ft * BN + k2 * 8] = v;
        }
      }
      __syncthreads();
    }
  }
}

// ---------------- combine: out[t] = w0*y[s0] + w1*y[s1] ----------------
__global__ __launch_bounds__(256) void combine_kernel(const float* __restrict__ y, const int* __restrict__ slot_of,
                                                      const float* __restrict__ assign_w, float* __restrict__ out) {
  int t = blockIdx.x;
  int d4 = threadIdx.x;
  int s0 = slot_of[2 * t], s1 = slot_of[2 * t + 1];
  float w0 = assign_w[2 * t], w1 = assign_w[2 * t + 1];
  float4 a = ((const float4*)(y + (size_t)s0 * D_MODEL))[d4];
  float4 b = ((const float4*)(y + (size_t)s1 * D_MODEL))[d4];
  float4 o;
  o.x = w0 * a.x + w1 * b.x;
  o.y = w0 * a.y + w1 * b.y;
  o.z = w0 * a.z + w1 * b.z;
  o.w = w0 * a.w + w1 * b.w;
  ((float4*)(out + (size_t)t * D_MODEL))[d4] = o;
}

extern "C" void kernel_launch(void* const* d_in, const int* in_sizes, int n_in,
                              void* d_out, int out_size, void* d_ws, size_t ws_size,
                              hipStream_t stream) {
  const float* x  = (const float*)d_in[0];
  const float* Wg = (const float*)d_in[1];
  const float* W1 = (const float*)d_in[2];
  const float* b1 = (const float*)d_in[3];
  const float* W2 = (const float*)d_in[4];
  const float* b2 = (const float*)d_in[5];
  float* out = (float*)d_out;
  char* ws = (char*)d_ws;

  // workspace layout (~285.6 MB)
  short* xb       = (short*)(ws);                       // 16,777,216 B
  short* w1t      = (short*)(ws + 16777216);            // 67,108,864 B  [e][f][k] bf16
  float* y        = (float*)(ws + 16777216);            // aliases w1t (dead after gemm1): 16384x1024 fp32
  short* w2t      = (short*)(ws + 83886080);            // 67,108,864 B  [e][d][ff] bf16
  short* H        = (short*)(ws + 150994944);           // 134,217,728 B 16384 x 4096 bf16
  int*   slot_tok = (int*)  (ws + 285212672);
  int*   assign_e = (int*)  (ws + 285278208);
  float* assign_w = (float*)(ws + 285343744);
  int*   slot_of  = (int*)  (ws + 285409280);
  int*   cnt_part = (int*)  (ws + 285474816);
  float* psum_part= (float*)(ws + 285540352);
  int*   ctrl     = (int*)  (ws + 285605888);
  int* cnt = ctrl; int* cursor = ctrl + 8; int* offs = ctrl + 16;

  hipFuncSetAttribute(reinterpret_cast<const void*>(&gemmT<256, 128, D_MODEL, D_FF, 32, 0>),
                      hipFuncAttributeMaxDynamicSharedMemorySize, 73728);
  hipFuncSetAttribute(reinterpret_cast<const void*>(&gemmT<128, 256, D_FF, D_MODEL, 64, 1>),
                      hipFuncAttributeMaxDynamicSharedMemorySize, 73728);

  zero_kernel<<<1, 64, 0, stream>>>(ctrl);
  transpose_conv<<<dim3(64, 16, NEXP), 256, 0, stream>>>(W1, w1t, D_MODEL, D_FF);
  transpose_conv<<<dim3(16, 64, NEXP), 256, 0, stream>>>(W2, w2t, D_FF, D_MODEL);
  gating_kernel<<<NGBLK, 256, 0, stream>>>(x, Wg, assign_e, assign_w, cnt_part, psum_part,
                                           (ushort4*)xb);
  scan_kernel<<<1, 256, 0, stream>>>(cnt_part, psum_part, cnt, offs, out + (out_size - 1));
  scatter_kernel<<<NASSIGN / 256, 256, 0, stream>>>(assign_e, offs, cursor, slot_tok, slot_of);
  // gemm1: 256M x 128N, RT=32, grid = RT*NP*8
  gemmT<256, 128, D_MODEL, D_FF, 32, 0><<<32 * (D_FF / 128) * 8, 512, 73728, stream>>>(
      xb, w1t, b1, slot_tok, cnt, offs, H);
  // gemm2: 128M x 256N, RT=64, grid = RT*NP*8
  gemmT<128, 256, D_FF, D_MODEL, 64, 1><<<64 * (D_MODEL / 256) * 8, 512, 73728, stream>>>(
      H, w2t, b2, slot_tok, cnt, offs, y);
  combine_kernel<<<NTOK, 256, 0, stream>>>(y, slot_of, assign_w, out);
}